// Round 1
// baseline (2757.354 us; speedup 1.0000x reference)
//
#include <hip/hip_runtime.h>
#include <hip/hip_bf16.h>
#include <cstdint>
#include <cstddef>

// ---------------------------------------------------------------------------
// Constellation CNN, fp32 correctness-first baseline.
// K1 (per-batch block): histogram -> class map -> conv1(table)+prelu+pool
//                       -> conv2+prelu+pool -> conv3+prelu+pool -> h3 (ws)
// K2: fc1 + prelu + fc2 -> out
// ---------------------------------------------------------------------------

__global__ __launch_bounds__(256, 2) void k_convstack(
    const float* __restrict__ x,
    const float* __restrict__ cw1, const float* __restrict__ cb1, const float* __restrict__ a1p,
    const float* __restrict__ cw2, const float* __restrict__ cb2, const float* __restrict__ a2p,
    const float* __restrict__ cw3, const float* __restrict__ cb3, const float* __restrict__ a3p,
    float* __restrict__ h3out)
{
    const int b = blockIdx.x;
    const int t = threadIdx.x;

    __shared__ int            hist[1024];     //  4 KB
    __shared__ unsigned char  cls[1024];      //  1 KB
    __shared__ float          w1t[864];       //  3.4 KB  (cw1 staged)
    __shared__ float          h1[32][16][16]; // 32 KB
    __shared__ float          h2[64][8][8];   // 16 KB   -> total ~56.4 KB

    // ---- phase 0: init ----
    for (int i = t; i < 1024; i += 256) hist[i] = 0;
    for (int i = t; i < 864; i += 256) w1t[i] = cw1[i];
    __syncthreads();

    // ---- phase 1: histogram (exact int counts; same fp32 op order as ref) ----
    const float* xb = x + (size_t)b * 2048;
    for (int n = t; n < 1024; n += 256) {
        float iv = xb[n];
        float qv = xb[1024 + n];
        bool valid = (iv >= -2.f) && (iv <= 2.f) && (qv >= -2.f) && (qv <= 2.f);
        if (valid) {
            int ii = (int)floorf((iv + 2.f) * 8.f);
            int qq = (int)floorf((qv + 2.f) * 8.f);
            ii = ii < 0 ? 0 : (ii > 31 ? 31 : ii);
            qq = qq < 0 ? 0 : (qq > 31 ? 31 : qq);
            atomicAdd(&hist[ii * 32 + qq], 1);
        }
    }
    __syncthreads();

    // ---- phase 2: class map. channel order [high, med, low] -> class 0/1/2 ----
    for (int i = t; i < 1024; i += 256) {
        int H = hist[i];
        cls[i] = (H > 15) ? 0 : ((H > 5) ? 1 : 2);
    }
    __syncthreads();

    const float a1 = *a1p, a2 = *a2p, a3 = *a3p;

    // ---- phase 3: conv1 (3x3, pad 1) via class table + prelu + 2x2 avgpool ----
    // input is one-hot over 3 classes => each tap is a table lookup, no multiply.
    for (int idx = t; idx < 8192; idx += 256) {
        const int oc = idx >> 8;
        const int r  = idx & 255;
        const int py = r >> 4, px = r & 15;
        const float bias = cb1[oc];
        const float* wt = &w1t[oc * 27];
        float s = 0.f;
        #pragma unroll
        for (int sy = 0; sy < 2; ++sy) {
            #pragma unroll
            for (int sx = 0; sx < 2; ++sx) {
                const int y = py * 2 + sy, xx = px * 2 + sx;
                float v = bias;
                #pragma unroll
                for (int ky = 0; ky < 3; ++ky) {
                    const int iy = y + ky - 1;
                    if (iy < 0 || iy > 31) continue;
                    #pragma unroll
                    for (int kx = 0; kx < 3; ++kx) {
                        const int ix = xx + kx - 1;
                        if (ix < 0 || ix > 31) continue;
                        v += wt[(int)cls[iy * 32 + ix] * 9 + ky * 3 + kx];
                    }
                }
                v = v >= 0.f ? v : a1 * v;
                s += v;
            }
        }
        h1[oc][py][px] = 0.25f * s;
    }
    __syncthreads();

    // ---- phase 4: conv2 (32->64, 3x3, pad 1) + prelu + pool -> h2 ----
    // thread: 16 out-channels x one pooled pixel (2x2 conv positions)
    {
        const int g  = t >> 6;           // 0..3  -> oc group of 16
        const int p  = t & 63;           // pooled pixel 0..63
        const int py = p >> 3, px = p & 7;
        const int oc0 = g * 16;

        float acc[16][4];
        #pragma unroll
        for (int o = 0; o < 16; ++o)
            #pragma unroll
            for (int q = 0; q < 4; ++q) acc[o][q] = 0.f;

        for (int ic = 0; ic < 32; ++ic) {
            float win[4][4];
            #pragma unroll
            for (int wy = 0; wy < 4; ++wy) {
                const int iy = 2 * py + wy - 1;
                #pragma unroll
                for (int wx = 0; wx < 4; ++wx) {
                    const int ix = 2 * px + wx - 1;
                    win[wy][wx] = (iy >= 0 && iy < 16 && ix >= 0 && ix < 16)
                                    ? h1[ic][iy][ix] : 0.f;
                }
            }
            #pragma unroll
            for (int ky = 0; ky < 3; ++ky) {
                #pragma unroll
                for (int kx = 0; kx < 3; ++kx) {
                    const float* wp = &cw2[(size_t)oc0 * 288 + ic * 9 + ky * 3 + kx];
                    #pragma unroll
                    for (int o = 0; o < 16; ++o) {
                        const float w = wp[o * 288];
                        acc[o][0] += w * win[ky + 0][kx + 0];
                        acc[o][1] += w * win[ky + 0][kx + 1];
                        acc[o][2] += w * win[ky + 1][kx + 0];
                        acc[o][3] += w * win[ky + 1][kx + 1];
                    }
                }
            }
        }
        #pragma unroll
        for (int o = 0; o < 16; ++o) {
            const float bb = cb2[oc0 + o];
            float s = 0.f;
            #pragma unroll
            for (int q = 0; q < 4; ++q) {
                float v = acc[o][q] + bb;
                v = v >= 0.f ? v : a2 * v;
                s += v;
            }
            h2[oc0 + o][py][px] = 0.25f * s;
        }
    }
    __syncthreads();

    // ---- phase 5: conv3 (64->128, 5x5, pad 2) + prelu + pool -> h3 (global) ----
    // thread: 8 out-channels x one pooled pixel (2x2 conv positions)
    {
        const int g  = t >> 4;           // 0..15 -> oc group of 8
        const int p  = t & 15;           // pooled pixel 0..15
        const int py = p >> 2, px = p & 3;
        const int oc0 = g * 8;

        float acc[8][4];
        #pragma unroll
        for (int o = 0; o < 8; ++o)
            #pragma unroll
            for (int q = 0; q < 4; ++q) acc[o][q] = 0.f;

        for (int ic = 0; ic < 64; ++ic) {
            float win[6][6];
            #pragma unroll
            for (int wy = 0; wy < 6; ++wy) {
                const int iy = 2 * py + wy - 2;
                #pragma unroll
                for (int wx = 0; wx < 6; ++wx) {
                    const int ix = 2 * px + wx - 2;
                    win[wy][wx] = (iy >= 0 && iy < 8 && ix >= 0 && ix < 8)
                                    ? h2[ic][iy][ix] : 0.f;
                }
            }
            #pragma unroll
            for (int ky = 0; ky < 5; ++ky) {
                #pragma unroll
                for (int kx = 0; kx < 5; ++kx) {
                    const float* wp = &cw3[(size_t)oc0 * 1600 + ic * 25 + ky * 5 + kx];
                    #pragma unroll
                    for (int o = 0; o < 8; ++o) {
                        const float w = wp[o * 1600];
                        acc[o][0] += w * win[ky + 0][kx + 0];
                        acc[o][1] += w * win[ky + 0][kx + 1];
                        acc[o][2] += w * win[ky + 1][kx + 0];
                        acc[o][3] += w * win[ky + 1][kx + 1];
                    }
                }
            }
        }
        #pragma unroll
        for (int o = 0; o < 8; ++o) {
            const float bb = cb3[oc0 + o];
            float s = 0.f;
            #pragma unroll
            for (int q = 0; q < 4; ++q) {
                float v = acc[o][q] + bb;
                v = v >= 0.f ? v : a3 * v;
                s += v;
            }
            // flatten layout: c*16 + y*4 + x ; p == py*4+px
            h3out[(size_t)b * 2048 + (oc0 + o) * 16 + p] = 0.25f * s;
        }
    }
}

// ---------------------------------------------------------------------------
// K2: fc1 (2048->256) + prelu + fc2 (256->128). One block = 16 batches.
// ---------------------------------------------------------------------------
__global__ __launch_bounds__(256) void k_fc(
    const float* __restrict__ h3,
    const float* __restrict__ fw1, const float* __restrict__ fb1, const float* __restrict__ a4p,
    const float* __restrict__ fw2, const float* __restrict__ fb2,
    float* __restrict__ out)
{
    const int t  = threadIdx.x;
    const int b0 = blockIdx.x * 16;

    __shared__ float As[16][128];   //  8 KB  activation K-chunk
    __shared__ float fT[16][256];   // 16 KB  fc1 output tile

    const int og = (t & 63) * 4;    // 4 consecutive oc
    const int bg = (t >> 6) * 4;    // 4 consecutive batches

    float acc[4][4];
    #pragma unroll
    for (int j = 0; j < 4; ++j)
        #pragma unroll
        for (int o = 0; o < 4; ++o) acc[j][o] = 0.f;

    const float a4 = *a4p;

    for (int kc = 0; kc < 2048; kc += 128) {
        __syncthreads();
        for (int i = t; i < 16 * 128; i += 256) {
            const int bl = i >> 7, kl = i & 127;
            As[bl][kl] = h3[(size_t)(b0 + bl) * 2048 + kc + kl];
        }
        __syncthreads();
        for (int k = 0; k < 128; ++k) {
            const float w0 = fw1[(size_t)(og + 0) * 2048 + kc + k];
            const float w1 = fw1[(size_t)(og + 1) * 2048 + kc + k];
            const float w2 = fw1[(size_t)(og + 2) * 2048 + kc + k];
            const float w3 = fw1[(size_t)(og + 3) * 2048 + kc + k];
            const float av0 = As[bg + 0][k];
            const float av1 = As[bg + 1][k];
            const float av2 = As[bg + 2][k];
            const float av3 = As[bg + 3][k];
            acc[0][0] += w0 * av0; acc[0][1] += w1 * av0; acc[0][2] += w2 * av0; acc[0][3] += w3 * av0;
            acc[1][0] += w0 * av1; acc[1][1] += w1 * av1; acc[1][2] += w2 * av1; acc[1][3] += w3 * av1;
            acc[2][0] += w0 * av2; acc[2][1] += w1 * av2; acc[2][2] += w2 * av2; acc[2][3] += w3 * av2;
            acc[3][0] += w0 * av3; acc[3][1] += w1 * av3; acc[3][2] += w2 * av3; acc[3][3] += w3 * av3;
        }
    }
    __syncthreads();

    // prelu + stash fc1 outputs
    #pragma unroll
    for (int j = 0; j < 4; ++j) {
        #pragma unroll
        for (int o = 0; o < 4; ++o) {
            float v = acc[j][o] + fb1[og + o];
            v = v >= 0.f ? v : a4 * v;
            fT[bg + j][og + o] = v;
        }
    }
    __syncthreads();

    // fc2: thread = (oc, batch-half of 8)
    {
        const int oc = t & 127;
        const int bh = t >> 7;
        float acc2[8];
        #pragma unroll
        for (int j = 0; j < 8; ++j) acc2[j] = 0.f;
        for (int k = 0; k < 256; ++k) {
            const float w = fw2[(size_t)oc * 256 + k];
            #pragma unroll
            for (int j = 0; j < 8; ++j) acc2[j] += w * fT[bh * 8 + j][k];
        }
        const float bb = fb2[oc];
        #pragma unroll
        for (int j = 0; j < 8; ++j)
            out[(size_t)(b0 + bh * 8 + j) * 128 + oc] = acc2[j] + bb;
    }
}

// ---------------------------------------------------------------------------
extern "C" void kernel_launch(void* const* d_in, const int* in_sizes, int n_in,
                              void* d_out, int out_size, void* d_ws, size_t ws_size,
                              hipStream_t stream)
{
    const float* x   = (const float*)d_in[0];
    const float* cw1 = (const float*)d_in[1];
    const float* cb1 = (const float*)d_in[2];
    const float* a1  = (const float*)d_in[3];
    const float* cw2 = (const float*)d_in[4];
    const float* cb2 = (const float*)d_in[5];
    const float* a2  = (const float*)d_in[6];
    const float* cw3 = (const float*)d_in[7];
    const float* cb3 = (const float*)d_in[8];
    const float* a3  = (const float*)d_in[9];
    const float* fw1 = (const float*)d_in[10];
    const float* fb1 = (const float*)d_in[11];
    const float* a4  = (const float*)d_in[12];
    const float* fw2 = (const float*)d_in[13];
    const float* fb2 = (const float*)d_in[14];
    float* out = (float*)d_out;
    float* h3  = (float*)d_ws;     // B x 2048 f32 = 33.6 MB

    const int B = in_sizes[0] / 2048;

    k_convstack<<<B, 256, 0, stream>>>(x, cw1, cb1, a1, cw2, cb2, a2,
                                       cw3, cb3, a3, h3);
    k_fc<<<B / 16, 256, 0, stream>>>(h3, fw1, fb1, a4, fw2, fb2, out);
}

// Round 2
// 609.518 us; speedup vs baseline: 4.5238x; 4.5238x over previous
//
#include <hip/hip_runtime.h>
#include <hip/hip_bf16.h>
#include <cstdint>
#include <cstddef>

typedef short short8 __attribute__((ext_vector_type(8)));
typedef float f32x4 __attribute__((ext_vector_type(4)));
typedef unsigned short u16x4 __attribute__((ext_vector_type(4)));

__device__ inline unsigned short f2b(float f) {
    union { __hip_bfloat16 h; unsigned short u; } cv;
    cv.h = __float2bfloat16(f);
    return cv.u;
}
__device__ inline float b2f(unsigned short u) {
    union { __hip_bfloat16 h; unsigned short u; } cv;
    cv.u = u;
    return __bfloat162float(cv.h);
}

// ---------------------------------------------------------------------------
// Prep: transpose+cast weights to bf16, K-contiguous layouts.
// cw1e  [32 oc][32 k]      k = tap*3+c (27 used, rest 0)
// cw2bf [9 tap][64 oc][32 ic]
// cw3bf [25 tap][128 oc][64 ic]
// ---------------------------------------------------------------------------
__global__ void k_prep(const float* __restrict__ cw1,
                       const float* __restrict__ cw2,
                       const float* __restrict__ cw3,
                       unsigned short* __restrict__ cw1e,
                       unsigned short* __restrict__ cw2bf,
                       unsigned short* __restrict__ cw3bf)
{
    const int i = blockIdx.x * 256 + threadIdx.x;
    if (i < 1024) {
        const int oc = i >> 5, k = i & 31;
        float v = 0.f;
        if (k < 27) { const int tap = k / 3, c = k - 3 * tap; v = cw1[oc * 27 + c * 9 + tap]; }
        cw1e[i] = f2b(v);
    }
    if (i < 18432) {
        const int tap = i >> 11, r = i & 2047, oc = r >> 5, ic = r & 31;
        cw2bf[i] = f2b(cw2[oc * 288 + ic * 9 + tap]);
    }
    for (int j = i; j < 204800; j += gridDim.x * 256) {
        const int tap = j >> 13, r = j & 8191, oc = r >> 6, ic = r & 63;
        cw3bf[j] = f2b(cw3[oc * 1600 + ic * 25 + tap]);
    }
}

// ---------------------------------------------------------------------------
// Conv stack: one block per batch, 256 threads = 4 waves.
// ---------------------------------------------------------------------------
__global__ __launch_bounds__(256) void k_convstack(
    const float* __restrict__ x,
    const unsigned short* __restrict__ cw1e, const float* __restrict__ cb1, const float* __restrict__ a1p,
    const unsigned short* __restrict__ cw2bf, const float* __restrict__ cb2, const float* __restrict__ a2p,
    const unsigned short* __restrict__ cw3bf, const float* __restrict__ cb3, const float* __restrict__ a3p,
    unsigned short* __restrict__ h3out)
{
    const int b = blockIdx.x;
    const int t = threadIdx.x;
    const int wv = t >> 6;        // wave 0..3
    const int l  = t & 63;        // lane
    const int lx = l & 15;
    const int q  = l >> 4;        // 0..3

    __shared__ int           hist[1024];        //  4 KB
    __shared__ unsigned char clsp[34 * 34];     //  1.2 KB (padded, border=255)
    __shared__ unsigned short h1p[256 * 40];    // 20 KB  [pos16][ic32 pad40] bf16
    __shared__ unsigned short h2p[64 * 72];     //  9 KB  [pos8][ic64 pad72] bf16

    // ---- init ----
    for (int i = t; i < 1024; i += 256) hist[i] = 0;
    for (int i = t; i < 34 * 34; i += 256) clsp[i] = 255;
    __syncthreads();

    // ---- histogram (exact int counts) ----
    const float* xb = x + (size_t)b * 2048;
    for (int n = t; n < 1024; n += 256) {
        const float iv = xb[n];
        const float qv = xb[1024 + n];
        if (iv >= -2.f && iv <= 2.f && qv >= -2.f && qv <= 2.f) {
            int ii = (int)floorf((iv + 2.f) * 8.f);
            int qq = (int)floorf((qv + 2.f) * 8.f);
            ii = ii < 0 ? 0 : (ii > 31 ? 31 : ii);
            qq = qq < 0 ? 0 : (qq > 31 ? 31 : qq);
            atomicAdd(&hist[ii * 32 + qq], 1);
        }
    }
    __syncthreads();

    // ---- class map: [high,med,low] -> 0/1/2 ----
    for (int i = t; i < 1024; i += 256) {
        const int H = hist[i];
        clsp[(i >> 5) * 34 + (i & 31) + 35] = (H > 15) ? 0 : ((H > 5) ? 1 : 2);
    }
    __syncthreads();

    const float a1 = *a1p, a2 = *a2p, a3 = *a3p;

    // ======== conv1 via one-hot MFMA: D[32oc][1024pos], K=32(27) ========
    {
        const int mt = wv & 1;        // oc half
        const int yh = wv >> 1;       // y half
        const short8 a1f = *(const short8*)(cw1e + (mt * 16 + lx) * 32 + q * 8);
        float b1r[4];
        #pragma unroll
        for (int r = 0; r < 4; ++r) b1r[r] = cb1[mt * 16 + q * 4 + r];

        for (int py = yh * 8; py < yh * 8 + 8; ++py) {
            f32x4 mac[4];
            #pragma unroll
            for (int d = 0; d < 4; ++d) {
                const int y = 2 * py + (d >> 1);
                const int xx = (d & 1) * 16 + lx;
                short8 bf;
                #pragma unroll
                for (int j = 0; j < 8; ++j) {
                    const int k = q * 8 + j;
                    const int tap = (k * 43) >> 7;          // k/3
                    const int c = k - 3 * tap;
                    const int ky = (tap * 43) >> 7;         // tap/3
                    const int kx = tap - 3 * ky;
                    const unsigned char cc = clsp[(y + ky) * 34 + (xx + kx)];
                    bf[j] = (k < 27 && cc == c) ? (short)0x3F80 : (short)0;
                }
                f32x4 z = {0.f, 0.f, 0.f, 0.f};
                mac[d] = __builtin_amdgcn_mfma_f32_16x16x32_bf16(a1f, bf, z, 0, 0, 0);
            }
            #pragma unroll
            for (int hx = 0; hx < 2; ++hx) {
                f32x4 u;
                #pragma unroll
                for (int r = 0; r < 4; ++r) {
                    float v0 = mac[hx][r] + b1r[r];     v0 = v0 >= 0.f ? v0 : a1 * v0;
                    float v1 = mac[2 + hx][r] + b1r[r]; v1 = v1 >= 0.f ? v1 : a1 * v1;
                    u[r] = v0 + v1;
                }
                #pragma unroll
                for (int r = 0; r < 4; ++r) u[r] += __shfl_xor(u[r], 1);
                if ((lx & 1) == 0) {
                    const int px = hx * 8 + (lx >> 1);
                    const int pos = py * 16 + px;
                    u16x4 pk;
                    #pragma unroll
                    for (int r = 0; r < 4; ++r) pk[r] = f2b(0.25f * u[r]);
                    *(u16x4*)(h1p + pos * 40 + mt * 16 + q * 4) = pk;
                }
            }
        }
    }
    __syncthreads();

    // ======== conv2: 9-tap GEMM, D[64oc][256pos], K=32/tap ========
    {
        short8 a2f[9];
        #pragma unroll
        for (int tap = 0; tap < 9; ++tap)
            a2f[tap] = *(const short8*)(cw2bf + tap * 2048 + (wv * 16 + lx) * 32 + q * 8);
        float b2r[4];
        #pragma unroll
        for (int r = 0; r < 4; ++r) b2r[r] = cb2[wv * 16 + q * 4 + r];

        for (int py = 0; py < 8; ++py) {
            f32x4 acc0 = {0.f, 0.f, 0.f, 0.f}, acc1 = {0.f, 0.f, 0.f, 0.f};
            #pragma unroll
            for (int tap = 0; tap < 9; ++tap) {
                const int ky = tap / 3, kx = tap % 3;
                const int sx = lx + kx - 1;
                const bool sxok = (unsigned)sx < 16u;
                #pragma unroll
                for (int dy = 0; dy < 2; ++dy) {
                    const int sy = 2 * py + dy + ky - 1;
                    if (sy >= 0 && sy < 16) {
                        short8 bf = {0, 0, 0, 0, 0, 0, 0, 0};
                        if (sxok) bf = *(const short8*)(h1p + (sy * 16 + sx) * 40 + q * 8);
                        if (dy == 0) acc0 = __builtin_amdgcn_mfma_f32_16x16x32_bf16(a2f[tap], bf, acc0, 0, 0, 0);
                        else         acc1 = __builtin_amdgcn_mfma_f32_16x16x32_bf16(a2f[tap], bf, acc1, 0, 0, 0);
                    }
                }
            }
            f32x4 u;
            #pragma unroll
            for (int r = 0; r < 4; ++r) {
                float v0 = acc0[r] + b2r[r]; v0 = v0 >= 0.f ? v0 : a2 * v0;
                float v1 = acc1[r] + b2r[r]; v1 = v1 >= 0.f ? v1 : a2 * v1;
                u[r] = v0 + v1;
            }
            #pragma unroll
            for (int r = 0; r < 4; ++r) u[r] += __shfl_xor(u[r], 1);
            if ((lx & 1) == 0) {
                const int pos = py * 8 + (lx >> 1);
                u16x4 pk;
                #pragma unroll
                for (int r = 0; r < 4; ++r) pk[r] = f2b(0.25f * u[r]);
                *(u16x4*)(h2p + pos * 72 + wv * 16 + q * 4) = pk;
            }
        }
    }
    __syncthreads();

    // ======== conv3: 25-tap GEMM, D[128oc][64pos], K=64/tap ========
    {
        f32x4 acc[2][4];
        #pragma unroll
        for (int mt = 0; mt < 2; ++mt)
            #pragma unroll
            for (int nt = 0; nt < 4; ++nt) { f32x4 z = {0.f,0.f,0.f,0.f}; acc[mt][nt] = z; }

        // software-pipelined A-frag loads (global, L2-hot)
        short8 aC[2][2], aN[2][2];
        #pragma unroll
        for (int mt = 0; mt < 2; ++mt)
            #pragma unroll
            for (int ks = 0; ks < 2; ++ks)
                aC[mt][ks] = *(const short8*)(cw3bf + (32 * wv + 16 * mt + lx) * 64 + ks * 32 + q * 8);

        for (int tap = 0; tap < 25; ++tap) {
            if (tap < 24) {
                #pragma unroll
                for (int mt = 0; mt < 2; ++mt)
                    #pragma unroll
                    for (int ks = 0; ks < 2; ++ks)
                        aN[mt][ks] = *(const short8*)(cw3bf + (tap + 1) * 8192 + (32 * wv + 16 * mt + lx) * 64 + ks * 32 + q * 8);
            }
            const int ky = (tap * 13) >> 6;        // tap/5
            const int kx = tap - 5 * ky;
            #pragma unroll
            for (int nt = 0; nt < 4; ++nt) {
                const int y = 2 * nt + (lx >> 3), xx = lx & 7;
                const int sy = y + ky - 2, sx = xx + kx - 2;
                const bool ok = (unsigned)sy < 8u && (unsigned)sx < 8u;
                const int soff = (sy * 8 + sx) * 72;
                #pragma unroll
                for (int ks = 0; ks < 2; ++ks) {
                    short8 bf = {0, 0, 0, 0, 0, 0, 0, 0};
                    if (ok) bf = *(const short8*)(h2p + soff + ks * 32 + q * 8);
                    acc[0][nt] = __builtin_amdgcn_mfma_f32_16x16x32_bf16(aC[0][ks], bf, acc[0][nt], 0, 0, 0);
                    acc[1][nt] = __builtin_amdgcn_mfma_f32_16x16x32_bf16(aC[1][ks], bf, acc[1][nt], 0, 0, 0);
                }
            }
            #pragma unroll
            for (int mt = 0; mt < 2; ++mt)
                #pragma unroll
                for (int ks = 0; ks < 2; ++ks) aC[mt][ks] = aN[mt][ks];
        }

        // epilogue: bias + prelu + 2x2 pool + global bf16 store
        #pragma unroll
        for (int mt = 0; mt < 2; ++mt) {
            float b3r[4];
            #pragma unroll
            for (int r = 0; r < 4; ++r) b3r[r] = cb3[32 * wv + 16 * mt + 4 * q + r];
            #pragma unroll
            for (int nt = 0; nt < 4; ++nt) {
                f32x4 u;
                #pragma unroll
                for (int r = 0; r < 4; ++r) {
                    float v = acc[mt][nt][r] + b3r[r];
                    v = v >= 0.f ? v : a3 * v;
                    u[r] = v;
                }
                #pragma unroll
                for (int r = 0; r < 4; ++r) u[r] += __shfl_xor(u[r], 1);
                #pragma unroll
                for (int r = 0; r < 4; ++r) u[r] += __shfl_xor(u[r], 8);
                if ((lx & 9) == 0) {
                    const int px = lx >> 1;     // 0..3
                    #pragma unroll
                    for (int r = 0; r < 4; ++r) {
                        const int oc = 32 * wv + 16 * mt + 4 * q + r;
                        h3out[(size_t)b * 2048 + oc * 16 + nt * 4 + px] = f2b(0.25f * u[r]);
                    }
                }
            }
        }
    }
}

// ---------------------------------------------------------------------------
// FC: fc1 (2048->256) fp32 + prelu + fc2 (256->128). One block = 16 batches.
// h3 input is bf16.
// ---------------------------------------------------------------------------
__global__ __launch_bounds__(256) void k_fc(
    const unsigned short* __restrict__ h3,
    const float* __restrict__ fw1, const float* __restrict__ fb1, const float* __restrict__ a4p,
    const float* __restrict__ fw2, const float* __restrict__ fb2,
    float* __restrict__ out)
{
    const int t  = threadIdx.x;
    const int b0 = blockIdx.x * 16;

    __shared__ float As[16][128];
    __shared__ float fT[16][256];

    const int og = (t & 63) * 4;
    const int bg = (t >> 6) * 4;

    float acc[4][4];
    #pragma unroll
    for (int j = 0; j < 4; ++j)
        #pragma unroll
        for (int o = 0; o < 4; ++o) acc[j][o] = 0.f;

    const float a4 = *a4p;

    for (int kc = 0; kc < 2048; kc += 128) {
        __syncthreads();
        for (int i = t; i < 16 * 128; i += 256) {
            const int bl = i >> 7, kl = i & 127;
            As[bl][kl] = b2f(h3[(size_t)(b0 + bl) * 2048 + kc + kl]);
        }
        __syncthreads();
        for (int k = 0; k < 128; ++k) {
            const float w0 = fw1[(size_t)(og + 0) * 2048 + kc + k];
            const float w1 = fw1[(size_t)(og + 1) * 2048 + kc + k];
            const float w2 = fw1[(size_t)(og + 2) * 2048 + kc + k];
            const float w3 = fw1[(size_t)(og + 3) * 2048 + kc + k];
            const float av0 = As[bg + 0][k];
            const float av1 = As[bg + 1][k];
            const float av2 = As[bg + 2][k];
            const float av3 = As[bg + 3][k];
            acc[0][0] += w0 * av0; acc[0][1] += w1 * av0; acc[0][2] += w2 * av0; acc[0][3] += w3 * av0;
            acc[1][0] += w0 * av1; acc[1][1] += w1 * av1; acc[1][2] += w2 * av1; acc[1][3] += w3 * av1;
            acc[2][0] += w0 * av2; acc[2][1] += w1 * av2; acc[2][2] += w2 * av2; acc[2][3] += w3 * av2;
            acc[3][0] += w0 * av3; acc[3][1] += w1 * av3; acc[3][2] += w2 * av3; acc[3][3] += w3 * av3;
        }
    }
    __syncthreads();

    #pragma unroll
    for (int j = 0; j < 4; ++j) {
        #pragma unroll
        for (int o = 0; o < 4; ++o) {
            float v = acc[j][o] + fb1[og + o];
            v = v >= 0.f ? v : a4 * v;
            fT[bg + j][og + o] = v;
        }
    }
    __syncthreads();

    {
        const int oc = t & 127;
        const int bh = t >> 7;
        float acc2[8];
        #pragma unroll
        for (int j = 0; j < 8; ++j) acc2[j] = 0.f;
        for (int k = 0; k < 256; ++k) {
            const float w = fw2[(size_t)oc * 256 + k];
            #pragma unroll
            for (int j = 0; j < 8; ++j) acc2[j] += w * fT[bh * 8 + j][k];
        }
        const float bb = fb2[oc];
        #pragma unroll
        for (int j = 0; j < 8; ++j)
            out[(size_t)(b0 + bh * 8 + j) * 128 + oc] = acc2[j] + bb;
    }
}

// ---------------------------------------------------------------------------
extern "C" void kernel_launch(void* const* d_in, const int* in_sizes, int n_in,
                              void* d_out, int out_size, void* d_ws, size_t ws_size,
                              hipStream_t stream)
{
    const float* x   = (const float*)d_in[0];
    const float* cw1 = (const float*)d_in[1];
    const float* cb1 = (const float*)d_in[2];
    const float* a1  = (const float*)d_in[3];
    const float* cw2 = (const float*)d_in[4];
    const float* cb2 = (const float*)d_in[5];
    const float* a2  = (const float*)d_in[6];
    const float* cw3 = (const float*)d_in[7];
    const float* cb3 = (const float*)d_in[8];
    const float* a3  = (const float*)d_in[9];
    const float* fw1 = (const float*)d_in[10];
    const float* fb1 = (const float*)d_in[11];
    const float* a4  = (const float*)d_in[12];
    const float* fw2 = (const float*)d_in[13];
    const float* fb2 = (const float*)d_in[14];
    float* out = (float*)d_out;

    // ws layout (bytes):
    //   [0,       2048)    cw1e   32x32 bf16
    //   [2048,    38912)   cw2bf  9x64x32 bf16
    //   [38912,   448512)  cw3bf  25x128x64 bf16
    //   [448512,  ...)     h3     4096x2048 bf16 (16.78 MB)
    unsigned short* cw1e  = (unsigned short*)((char*)d_ws);
    unsigned short* cw2bf = (unsigned short*)((char*)d_ws + 2048);
    unsigned short* cw3bf = (unsigned short*)((char*)d_ws + 38912);
    unsigned short* h3    = (unsigned short*)((char*)d_ws + 448512);

    const int B = in_sizes[0] / 2048;

    k_prep<<<800, 256, 0, stream>>>(cw1, cw2, cw3, cw1e, cw2bf, cw3bf);
    k_convstack<<<B, 256, 0, stream>>>(x, cw1e, cb1, a1, cw2bf, cb2, a2,
                                       cw3bf, cb3, a3, h3);
    k_fc<<<B / 16, 256, 0, stream>>>(h3, fw1, fb1, a4, fw2, fb2, out);
}

// Round 3
// 366.297 us; speedup vs baseline: 7.5276x; 1.6640x over previous
//
#include <hip/hip_runtime.h>
#include <hip/hip_bf16.h>
#include <cstdint>
#include <cstddef>

typedef short short8 __attribute__((ext_vector_type(8)));
typedef float f32x4 __attribute__((ext_vector_type(4)));
typedef unsigned short u16x4 __attribute__((ext_vector_type(4)));

__device__ inline unsigned short f2b(float f) {
    union { __hip_bfloat16 h; unsigned short u; } cv;
    cv.h = __float2bfloat16(f);
    return cv.u;
}
__device__ inline float b2f(unsigned short u) {
    union { __hip_bfloat16 h; unsigned short u; } cv;
    cv.u = u;
    return __bfloat162float(cv.h);
}

// ---------------------------------------------------------------------------
// Prep: transpose+cast weights.
// cw1e  [32 oc][32 k]          k = tap*3+c (27 used, rest 0)       bf16
// cw2bf [9 tap][64 oc][32 ic]                                      bf16
// cw3bf [25 tap][128 oc][64 ic]                                    bf16
// fw1hi/fw1lo [k/8][256 oc][8] hi/lo bf16 split of fw1 (fp32 grade)
// fw2t  [256 k][128 oc]        fp32 transpose of fw2
// ---------------------------------------------------------------------------
__global__ void k_prep(const float* __restrict__ cw1,
                       const float* __restrict__ cw2,
                       const float* __restrict__ cw3,
                       const float* __restrict__ fw1,
                       const float* __restrict__ fw2,
                       unsigned short* __restrict__ cw1e,
                       unsigned short* __restrict__ cw2bf,
                       unsigned short* __restrict__ cw3bf,
                       unsigned short* __restrict__ fw1hi,
                       unsigned short* __restrict__ fw1lo,
                       float* __restrict__ fw2t)
{
    const int i = blockIdx.x * 256 + threadIdx.x;
    const int stride = gridDim.x * 256;
    if (i < 1024) {
        const int oc = i >> 5, k = i & 31;
        float v = 0.f;
        if (k < 27) { const int tap = k / 3, c = k - 3 * tap; v = cw1[oc * 27 + c * 9 + tap]; }
        cw1e[i] = f2b(v);
    }
    if (i < 18432) {
        const int tap = i >> 11, r = i & 2047, oc = r >> 5, ic = r & 31;
        cw2bf[i] = f2b(cw2[oc * 288 + ic * 9 + tap]);
    }
    for (int j = i; j < 204800; j += stride) {
        const int tap = j >> 13, r = j & 8191, oc = r >> 6, ic = r & 63;
        cw3bf[j] = f2b(cw3[oc * 1600 + ic * 25 + tap]);
    }
    for (int j = i; j < 524288; j += stride) {
        const int oc = j >> 11, k = j & 2047;
        const float w = fw1[j];
        const unsigned short hi = f2b(w);
        const unsigned short lo = f2b(w - b2f(hi));
        const size_t o = ((size_t)(k >> 3) * 256 + oc) * 8 + (k & 7);
        fw1hi[o] = hi; fw1lo[o] = lo;
    }
    for (int j = i; j < 32768; j += stride) {
        const int k = j >> 7, oc = j & 127;
        fw2t[j] = fw2[oc * 256 + k];
    }
}

// ---------------------------------------------------------------------------
// Conv stack: one block per batch, 256 threads = 4 waves. (unchanged)
// ---------------------------------------------------------------------------
__global__ __launch_bounds__(256) void k_convstack(
    const float* __restrict__ x,
    const unsigned short* __restrict__ cw1e, const float* __restrict__ cb1, const float* __restrict__ a1p,
    const unsigned short* __restrict__ cw2bf, const float* __restrict__ cb2, const float* __restrict__ a2p,
    const unsigned short* __restrict__ cw3bf, const float* __restrict__ cb3, const float* __restrict__ a3p,
    unsigned short* __restrict__ h3out)
{
    const int b = blockIdx.x;
    const int t = threadIdx.x;
    const int wv = t >> 6;        // wave 0..3
    const int l  = t & 63;        // lane
    const int lx = l & 15;
    const int q  = l >> 4;        // 0..3

    __shared__ int           hist[1024];        //  4 KB
    __shared__ unsigned char clsp[34 * 34];     //  1.2 KB (padded, border=255)
    __shared__ unsigned short h1p[256 * 40];    // 20 KB  [pos16][ic32 pad40] bf16
    __shared__ unsigned short h2p[64 * 72];     //  9 KB  [pos8][ic64 pad72] bf16

    // ---- init ----
    for (int i = t; i < 1024; i += 256) hist[i] = 0;
    for (int i = t; i < 34 * 34; i += 256) clsp[i] = 255;
    __syncthreads();

    // ---- histogram (exact int counts) ----
    const float* xb = x + (size_t)b * 2048;
    for (int n = t; n < 1024; n += 256) {
        const float iv = xb[n];
        const float qv = xb[1024 + n];
        if (iv >= -2.f && iv <= 2.f && qv >= -2.f && qv <= 2.f) {
            int ii = (int)floorf((iv + 2.f) * 8.f);
            int qq = (int)floorf((qv + 2.f) * 8.f);
            ii = ii < 0 ? 0 : (ii > 31 ? 31 : ii);
            qq = qq < 0 ? 0 : (qq > 31 ? 31 : qq);
            atomicAdd(&hist[ii * 32 + qq], 1);
        }
    }
    __syncthreads();

    // ---- class map: [high,med,low] -> 0/1/2 ----
    for (int i = t; i < 1024; i += 256) {
        const int H = hist[i];
        clsp[(i >> 5) * 34 + (i & 31) + 35] = (H > 15) ? 0 : ((H > 5) ? 1 : 2);
    }
    __syncthreads();

    const float a1 = *a1p, a2 = *a2p, a3 = *a3p;

    // ======== conv1 via one-hot MFMA: D[32oc][1024pos], K=32(27) ========
    {
        const int mt = wv & 1;        // oc half
        const int yh = wv >> 1;       // y half
        const short8 a1f = *(const short8*)(cw1e + (mt * 16 + lx) * 32 + q * 8);
        float b1r[4];
        #pragma unroll
        for (int r = 0; r < 4; ++r) b1r[r] = cb1[mt * 16 + q * 4 + r];

        for (int py = yh * 8; py < yh * 8 + 8; ++py) {
            f32x4 mac[4];
            #pragma unroll
            for (int d = 0; d < 4; ++d) {
                const int y = 2 * py + (d >> 1);
                const int xx = (d & 1) * 16 + lx;
                short8 bf;
                #pragma unroll
                for (int j = 0; j < 8; ++j) {
                    const int k = q * 8 + j;
                    const int tap = (k * 43) >> 7;          // k/3
                    const int c = k - 3 * tap;
                    const int ky = (tap * 43) >> 7;         // tap/3
                    const int kx = tap - 3 * ky;
                    const unsigned char cc = clsp[(y + ky) * 34 + (xx + kx)];
                    bf[j] = (k < 27 && cc == c) ? (short)0x3F80 : (short)0;
                }
                f32x4 z = {0.f, 0.f, 0.f, 0.f};
                mac[d] = __builtin_amdgcn_mfma_f32_16x16x32_bf16(a1f, bf, z, 0, 0, 0);
            }
            #pragma unroll
            for (int hx = 0; hx < 2; ++hx) {
                f32x4 u;
                #pragma unroll
                for (int r = 0; r < 4; ++r) {
                    float v0 = mac[hx][r] + b1r[r];     v0 = v0 >= 0.f ? v0 : a1 * v0;
                    float v1 = mac[2 + hx][r] + b1r[r]; v1 = v1 >= 0.f ? v1 : a1 * v1;
                    u[r] = v0 + v1;
                }
                #pragma unroll
                for (int r = 0; r < 4; ++r) u[r] += __shfl_xor(u[r], 1);
                if ((lx & 1) == 0) {
                    const int px = hx * 8 + (lx >> 1);
                    const int pos = py * 16 + px;
                    u16x4 pk;
                    #pragma unroll
                    for (int r = 0; r < 4; ++r) pk[r] = f2b(0.25f * u[r]);
                    *(u16x4*)(h1p + pos * 40 + mt * 16 + q * 4) = pk;
                }
            }
        }
    }
    __syncthreads();

    // ======== conv2: 9-tap GEMM, D[64oc][256pos], K=32/tap ========
    {
        short8 a2f[9];
        #pragma unroll
        for (int tap = 0; tap < 9; ++tap)
            a2f[tap] = *(const short8*)(cw2bf + tap * 2048 + (wv * 16 + lx) * 32 + q * 8);
        float b2r[4];
        #pragma unroll
        for (int r = 0; r < 4; ++r) b2r[r] = cb2[wv * 16 + q * 4 + r];

        for (int py = 0; py < 8; ++py) {
            f32x4 acc0 = {0.f, 0.f, 0.f, 0.f}, acc1 = {0.f, 0.f, 0.f, 0.f};
            #pragma unroll
            for (int tap = 0; tap < 9; ++tap) {
                const int ky = tap / 3, kx = tap % 3;
                const int sx = lx + kx - 1;
                const bool sxok = (unsigned)sx < 16u;
                #pragma unroll
                for (int dy = 0; dy < 2; ++dy) {
                    const int sy = 2 * py + dy + ky - 1;
                    if (sy >= 0 && sy < 16) {
                        short8 bf = {0, 0, 0, 0, 0, 0, 0, 0};
                        if (sxok) bf = *(const short8*)(h1p + (sy * 16 + sx) * 40 + q * 8);
                        if (dy == 0) acc0 = __builtin_amdgcn_mfma_f32_16x16x32_bf16(a2f[tap], bf, acc0, 0, 0, 0);
                        else         acc1 = __builtin_amdgcn_mfma_f32_16x16x32_bf16(a2f[tap], bf, acc1, 0, 0, 0);
                    }
                }
            }
            f32x4 u;
            #pragma unroll
            for (int r = 0; r < 4; ++r) {
                float v0 = acc0[r] + b2r[r]; v0 = v0 >= 0.f ? v0 : a2 * v0;
                float v1 = acc1[r] + b2r[r]; v1 = v1 >= 0.f ? v1 : a2 * v1;
                u[r] = v0 + v1;
            }
            #pragma unroll
            for (int r = 0; r < 4; ++r) u[r] += __shfl_xor(u[r], 1);
            if ((lx & 1) == 0) {
                const int pos = py * 8 + (lx >> 1);
                u16x4 pk;
                #pragma unroll
                for (int r = 0; r < 4; ++r) pk[r] = f2b(0.25f * u[r]);
                *(u16x4*)(h2p + pos * 72 + wv * 16 + q * 4) = pk;
            }
        }
    }
    __syncthreads();

    // ======== conv3: 25-tap GEMM, D[128oc][64pos], K=64/tap ========
    {
        f32x4 acc[2][4];
        #pragma unroll
        for (int mt = 0; mt < 2; ++mt)
            #pragma unroll
            for (int nt = 0; nt < 4; ++nt) { f32x4 z = {0.f,0.f,0.f,0.f}; acc[mt][nt] = z; }

        short8 aC[2][2], aN[2][2];
        #pragma unroll
        for (int mt = 0; mt < 2; ++mt)
            #pragma unroll
            for (int ks = 0; ks < 2; ++ks)
                aC[mt][ks] = *(const short8*)(cw3bf + (32 * wv + 16 * mt + lx) * 64 + ks * 32 + q * 8);

        for (int tap = 0; tap < 25; ++tap) {
            if (tap < 24) {
                #pragma unroll
                for (int mt = 0; mt < 2; ++mt)
                    #pragma unroll
                    for (int ks = 0; ks < 2; ++ks)
                        aN[mt][ks] = *(const short8*)(cw3bf + (tap + 1) * 8192 + (32 * wv + 16 * mt + lx) * 64 + ks * 32 + q * 8);
            }
            const int ky = (tap * 13) >> 6;        // tap/5
            const int kx = tap - 5 * ky;
            #pragma unroll
            for (int nt = 0; nt < 4; ++nt) {
                const int y = 2 * nt + (lx >> 3), xx = lx & 7;
                const int sy = y + ky - 2, sx = xx + kx - 2;
                const bool ok = (unsigned)sy < 8u && (unsigned)sx < 8u;
                const int soff = (sy * 8 + sx) * 72;
                #pragma unroll
                for (int ks = 0; ks < 2; ++ks) {
                    short8 bf = {0, 0, 0, 0, 0, 0, 0, 0};
                    if (ok) bf = *(const short8*)(h2p + soff + ks * 32 + q * 8);
                    acc[0][nt] = __builtin_amdgcn_mfma_f32_16x16x32_bf16(aC[0][ks], bf, acc[0][nt], 0, 0, 0);
                    acc[1][nt] = __builtin_amdgcn_mfma_f32_16x16x32_bf16(aC[1][ks], bf, acc[1][nt], 0, 0, 0);
                }
            }
            #pragma unroll
            for (int mt = 0; mt < 2; ++mt)
                #pragma unroll
                for (int ks = 0; ks < 2; ++ks) aC[mt][ks] = aN[mt][ks];
        }

        // epilogue: bias + prelu + 2x2 pool + global bf16 store
        #pragma unroll
        for (int mt = 0; mt < 2; ++mt) {
            float b3r[4];
            #pragma unroll
            for (int r = 0; r < 4; ++r) b3r[r] = cb3[32 * wv + 16 * mt + 4 * q + r];
            #pragma unroll
            for (int nt = 0; nt < 4; ++nt) {
                f32x4 u;
                #pragma unroll
                for (int r = 0; r < 4; ++r) {
                    float v = acc[mt][nt][r] + b3r[r];
                    v = v >= 0.f ? v : a3 * v;
                    u[r] = v;
                }
                #pragma unroll
                for (int r = 0; r < 4; ++r) u[r] += __shfl_xor(u[r], 1);
                #pragma unroll
                for (int r = 0; r < 4; ++r) u[r] += __shfl_xor(u[r], 8);
                if ((lx & 9) == 0) {
                    const int px = lx >> 1;     // 0..3
                    #pragma unroll
                    for (int r = 0; r < 4; ++r) {
                        const int oc = 32 * wv + 16 * mt + 4 * q + r;
                        h3out[(size_t)b * 2048 + oc * 16 + nt * 4 + px] = f2b(0.25f * u[r]);
                    }
                }
            }
        }
    }
}

// ---------------------------------------------------------------------------
// FC via MFMA: fc1 = (fw1hi + fw1lo) @ h3, fp32-grade. fc2 fp32 VALU.
// 128 blocks x 512 threads (8 waves); 32 batches/block; M=256 oc; K=2048.
// ---------------------------------------------------------------------------
__global__ __launch_bounds__(512) void k_fc(
    const unsigned short* __restrict__ fw1hi,
    const unsigned short* __restrict__ fw1lo,
    const unsigned short* __restrict__ h3,
    const float* __restrict__ fb1, const float* __restrict__ a4p,
    const float* __restrict__ fw2t, const float* __restrict__ fb2,
    float* __restrict__ out)
{
    const int t  = threadIdx.x;
    const int wv = t >> 6;          // wave 0..7
    const int l  = t & 63;
    const int lx = l & 15;
    const int q  = l >> 4;          // 0..3
    const int b0 = blockIdx.x * 32;

    __shared__ unsigned short Bs[32 * 128];   //  8 KB  h3 K-chunk, swizzled
    __shared__ float fT[256 * 34];            // 34 KB  fc1 out [oc][batch pad34]

    f32x4 acc[2][2];
    #pragma unroll
    for (int mt = 0; mt < 2; ++mt)
        #pragma unroll
        for (int bn = 0; bn < 2; ++bn) { f32x4 z = {0.f,0.f,0.f,0.f}; acc[mt][bn] = z; }

    // staging geometry: thread -> (row, 16B col), source col XOR-swizzled
    const int srow  = t >> 4;                 // 0..31
    const int scolb = (t & 15) << 4;          // 0..240 byte col
    const unsigned short* gsrc = h3 + (size_t)(b0 + srow) * 2048
                               + ((scolb ^ ((srow & 7) << 4)) >> 1);

    for (int kc = 0; kc < 2048; kc += 128) {
        __builtin_amdgcn_global_load_lds(
            (const __attribute__((address_space(1))) unsigned int*)(gsrc + kc),
            (__attribute__((address_space(3))) unsigned int*)(Bs + t * 8),
            16, 0, 0);
        __syncthreads();   // drains vmcnt, all rows staged

        #pragma unroll
        for (int s = 0; s < 4; ++s) {
            const int kb = ((kc + s * 32) >> 3) + q;    // k/8 block index
            const short8 ah0 = *(const short8*)(fw1hi + ((size_t)kb * 256 + wv * 32 + lx) * 8);
            const short8 ah1 = *(const short8*)(fw1hi + ((size_t)kb * 256 + wv * 32 + 16 + lx) * 8);
            const short8 al0 = *(const short8*)(fw1lo + ((size_t)kb * 256 + wv * 32 + lx) * 8);
            const short8 al1 = *(const short8*)(fw1lo + ((size_t)kb * 256 + wv * 32 + 16 + lx) * 8);
            #pragma unroll
            for (int bn = 0; bn < 2; ++bn) {
                const int rr = bn * 16 + lx;
                const short8 bfr = *(const short8*)((const char*)Bs + rr * 256
                                    + ((s * 64 + q * 16) ^ ((rr & 7) << 4)));
                acc[0][bn] = __builtin_amdgcn_mfma_f32_16x16x32_bf16(ah0, bfr, acc[0][bn], 0, 0, 0);
                acc[1][bn] = __builtin_amdgcn_mfma_f32_16x16x32_bf16(ah1, bfr, acc[1][bn], 0, 0, 0);
                acc[0][bn] = __builtin_amdgcn_mfma_f32_16x16x32_bf16(al0, bfr, acc[0][bn], 0, 0, 0);
                acc[1][bn] = __builtin_amdgcn_mfma_f32_16x16x32_bf16(al1, bfr, acc[1][bn], 0, 0, 0);
            }
        }
        __syncthreads();   // before next stage overwrites Bs
    }

    // fc1 epilogue: bias + prelu -> fT[oc][batch]
    const float a4 = *a4p;
    #pragma unroll
    for (int mt = 0; mt < 2; ++mt) {
        #pragma unroll
        for (int r = 0; r < 4; ++r) {
            const int oc = wv * 32 + mt * 16 + q * 4 + r;
            const float bb = fb1[oc];
            #pragma unroll
            for (int bn = 0; bn < 2; ++bn) {
                float v = acc[mt][bn][r] + bb;
                v = v >= 0.f ? v : a4 * v;
                fT[oc * 34 + bn * 16 + lx] = v;
            }
        }
    }
    __syncthreads();

    // fc2: 128 oc x 32 batches, fp32 VALU. thread -> (oc2, 8 batches)
    {
        const int oc2 = t & 127;
        const int bh  = t >> 7;            // 0..3
        float acc2[8];
        #pragma unroll
        for (int j = 0; j < 8; ++j) acc2[j] = 0.f;
        for (int k = 0; k < 256; ++k) {
            const float w = fw2t[k * 128 + oc2];
            const float* fr = &fT[k * 34 + bh * 8];
            #pragma unroll
            for (int j = 0; j < 8; ++j) acc2[j] += w * fr[j];
        }
        const float bb = fb2[oc2];
        #pragma unroll
        for (int j = 0; j < 8; ++j)
            out[(size_t)(b0 + bh * 8 + j) * 128 + oc2] = acc2[j] + bb;
    }
}

// ---------------------------------------------------------------------------
extern "C" void kernel_launch(void* const* d_in, const int* in_sizes, int n_in,
                              void* d_out, int out_size, void* d_ws, size_t ws_size,
                              hipStream_t stream)
{
    const float* x   = (const float*)d_in[0];
    const float* cw1 = (const float*)d_in[1];
    const float* cb1 = (const float*)d_in[2];
    const float* a1  = (const float*)d_in[3];
    const float* cw2 = (const float*)d_in[4];
    const float* cb2 = (const float*)d_in[5];
    const float* a2  = (const float*)d_in[6];
    const float* cw3 = (const float*)d_in[7];
    const float* cb3 = (const float*)d_in[8];
    const float* a3  = (const float*)d_in[9];
    const float* fw1 = (const float*)d_in[10];
    const float* fb1 = (const float*)d_in[11];
    const float* a4  = (const float*)d_in[12];
    const float* fw2 = (const float*)d_in[13];
    const float* fb2 = (const float*)d_in[14];
    float* out = (float*)d_out;

    // ws layout (bytes):
    //   [0,        2048)     cw1e   32x32 bf16
    //   [2048,     38912)    cw2bf  9x64x32 bf16
    //   [38912,    448512)   cw3bf  25x128x64 bf16
    //   [448512,   1497088)  fw1hi  [k/8][256][8] bf16
    //   [1497088,  2545664)  fw1lo  [k/8][256][8] bf16
    //   [2545664,  2676736)  fw2t   [256][128] f32
    //   [2676736,  19453952) h3     4096x2048 bf16
    unsigned short* cw1e  = (unsigned short*)((char*)d_ws);
    unsigned short* cw2bf = (unsigned short*)((char*)d_ws + 2048);
    unsigned short* cw3bf = (unsigned short*)((char*)d_ws + 38912);
    unsigned short* fw1hi = (unsigned short*)((char*)d_ws + 448512);
    unsigned short* fw1lo = (unsigned short*)((char*)d_ws + 1497088);
    float*          fw2t  = (float*)((char*)d_ws + 2545664);
    unsigned short* h3    = (unsigned short*)((char*)d_ws + 2676736);

    const int B = in_sizes[0] / 2048;

    k_prep<<<800, 256, 0, stream>>>(cw1, cw2, cw3, fw1, fw2,
                                    cw1e, cw2bf, cw3bf, fw1hi, fw1lo, fw2t);
    k_convstack<<<B, 256, 0, stream>>>(x, cw1e, cb1, a1, cw2bf, cb2, a2,
                                       cw3bf, cb3, a3, h3);
    k_fc<<<B / 32, 512, 0, stream>>>(fw1hi, fw1lo, h3, fb1, a4, fw2t, fb2, out);
}